// Round 2
// baseline (277.733 us; speedup 1.0000x reference)
//
#include <hip/hip_runtime.h>

// PointPillarScatter: scatter sparse pillar features into a dense BEV grid.
// Grid: NX=432, NY=496, NZ=1, C=64, B=8, P=96000 pillars (5.6% occupancy).
// Out 0: [B, C, NY, NX] f32 ; Out 1: [B, 1, NY, NX] f32, concatenated flat.
//
// Strategy: invert the scatter into a gather so the 446 MB output is written
// exactly once, fully coalesced.
//   1) map[B*S] (int32, in d_ws) = -1            (hipMemsetAsync 0xFF)
//   2) map[b*S + z + y*NX + x] = pillar index    (96k-thread scatter, tiny)
//   3) fill: thread = 4 consecutive spatial cells; loop 64 channels writing
//      float4; all-empty groups (~79% of threads) write zeros with no loads.

namespace {

constexpr int kNX = 432;
constexpr int kNY = 496;
constexpr int kS  = kNX * kNY;   // 214272 spatial cells per sample
constexpr int kC  = 64;          // bev features

__global__ void scatter_idx_kernel(const int* __restrict__ coords,
                                   int* __restrict__ map,
                                   int P, int BS) {
  int p = blockIdx.x * blockDim.x + threadIdx.x;
  if (p >= P) return;
  // coords row p = (b, z, y, x) as int32
  int4 c = reinterpret_cast<const int4*>(coords)[p];
  long flat = (long)c.x * kS + (long)c.y + (long)c.z * kNX + (long)c.w;
  if (flat >= 0 && flat < (long)BS) map[(int)flat] = p;
}

__global__ __launch_bounds__(256) void fill_kernel(
    const int* __restrict__ map,
    const float* __restrict__ pf,    // [P, 64]
    const float* __restrict__ vnp,   // [P]
    float* __restrict__ out,
    int B) {
  // one thread = 4 consecutive spatial cells (float4 / int4 lanes).
  // kS % 4 == 0, so a thread's 4 cells never straddle a batch boundary.
  int t = blockIdx.x * blockDim.x + threadIdx.x;
  int gpos = t * 4;
  int BS = B * kS;
  if (gpos >= BS) return;
  int b = gpos / kS;
  int s = gpos - b * kS;

  int4 m = reinterpret_cast<const int4*>(map)[t];

  // points output (offset B*C*S), one float4 per thread
  float4 pts;
  pts.x = (m.x >= 0) ? vnp[m.x] : 0.0f;
  pts.y = (m.y >= 0) ? vnp[m.y] : 0.0f;
  pts.z = (m.z >= 0) ? vnp[m.z] : 0.0f;
  pts.w = (m.w >= 0) ? vnp[m.w] : 0.0f;
  *reinterpret_cast<float4*>(out + B * kC * kS + gpos) = pts;

  // feature output: 64 channel planes, each write float4 coalesced per wave
  float* outb = out + b * kC * kS + s;
  // occupied iff index >= 0; -1 means empty.  (Round-0 bug: bitwise OR of
  // -1 made this "all occupied" instead of "any occupied".)
  bool any = (m.x >= 0) | (m.y >= 0) | (m.z >= 0) | (m.w >= 0);
  if (!any) {
    float4 z4 = make_float4(0.f, 0.f, 0.f, 0.f);
    #pragma unroll 8
    for (int c = 0; c < kC; ++c) {
      *reinterpret_cast<float4*>(outb + c * kS) = z4;
    }
  } else {
    const float* px = (m.x >= 0) ? pf + m.x * kC : nullptr;
    const float* py = (m.y >= 0) ? pf + m.y * kC : nullptr;
    const float* pz = (m.z >= 0) ? pf + m.z * kC : nullptr;
    const float* pw = (m.w >= 0) ? pf + m.w * kC : nullptr;
    #pragma unroll 8
    for (int c = 0; c < kC; ++c) {
      float4 v;
      v.x = px ? px[c] : 0.0f;
      v.y = py ? py[c] : 0.0f;
      v.z = pz ? pz[c] : 0.0f;
      v.w = pw ? pw[c] : 0.0f;
      *reinterpret_cast<float4*>(outb + c * kS) = v;
    }
  }
}

// ---- fallback if ws_size is too small for the map: memset + direct scatter
__global__ void direct_scatter_kernel(const int* __restrict__ coords,
                                      const float* __restrict__ pf,
                                      const float* __restrict__ vnp,
                                      float* __restrict__ out,
                                      int P, int B) {
  int p = blockIdx.x;          // one wave per pillar
  int c = threadIdx.x;         // 64 channels
  if (p >= P) return;
  int4 cc = reinterpret_cast<const int4*>(coords)[p];
  int b = cc.x;
  int s = cc.y + cc.z * kNX + cc.w;
  out[(b * kC + c) * kS + s] = pf[p * kC + c];
  if (c == 0) out[B * kC * kS + b * kS + s] = vnp[p];
}

}  // namespace

extern "C" void kernel_launch(void* const* d_in, const int* in_sizes, int n_in,
                              void* d_out, int out_size, void* d_ws, size_t ws_size,
                              hipStream_t stream) {
  const float* pf     = (const float*)d_in[0];  // [P,64] f32
  const int*   coords = (const int*)d_in[1];    // [P,4] int32 (b,z,y,x)
  const float* vnp    = (const float*)d_in[2];  // [P] f32
  const int B = 8;                               // fixed by problem config
  const int P = in_sizes[0] / kC;
  const int BS = B * kS;                         // 1,714,176
  float* out = (float*)d_out;

  const size_t map_bytes = (size_t)BS * sizeof(int);
  if (ws_size >= map_bytes) {
    int* map = (int*)d_ws;
    hipMemsetAsync(map, 0xFF, map_bytes, stream);  // all -1
    scatter_idx_kernel<<<(P + 255) / 256, 256, 0, stream>>>(coords, map, P, BS);
    const int threads = BS / 4;                    // 428,544
    fill_kernel<<<(threads + 255) / 256, 256, 0, stream>>>(map, pf, vnp, out, B);
  } else {
    hipMemsetAsync(out, 0, (size_t)out_size * sizeof(float), stream);
    direct_scatter_kernel<<<P, 64, 0, stream>>>(coords, pf, vnp, out, P, B);
  }
}

// Round 3
// 116.499 us; speedup vs baseline: 2.3840x; 2.3840x over previous
//
#include <hip/hip_runtime.h>

// PointPillarScatter: scatter sparse pillar features into a dense BEV grid.
// Grid: NX=432, NY=496, NZ=1, C=64, B=8, P=96000 pillars (5.6% occupancy).
// Out 0: [B, C, NY, NX] f32 ; Out 1: [B, 1, NY, NX] f32, concatenated flat.
//
// Round-2 restructure: the round-1 fill wrote 64 channel planes per thread
// (1 KB bursts strided 857 KB apart) -> 2.3 TB/s, 1.36x write amplification.
// Now the OUTPUT is swept linearly: thread g owns output float4 g; it derives
// (plane, j) and gathers. Writes are one long stream (the harness's own
// memset hits 6.3 TB/s with this pattern). Map is L2-resident per batch,
// pillar features are L3-resident, so repeated reads stay off HBM.

namespace {

constexpr int kNX = 432;
constexpr int kNY = 496;
constexpr int kS  = kNX * kNY;   // 214272 spatial cells per sample
constexpr int kS4 = kS / 4;      // 53568 float4s per plane
constexpr int kC  = 64;
constexpr int kB  = 8;

__global__ void scatter_idx_kernel(const int* __restrict__ coords,
                                   int* __restrict__ map,
                                   int P, int BS) {
  int p = blockIdx.x * blockDim.x + threadIdx.x;
  if (p >= P) return;
  // coords row p = (b, z, y, x) as int32
  int4 c = reinterpret_cast<const int4*>(coords)[p];
  long flat = (long)c.x * kS + (long)c.y + (long)c.z * kNX + (long)c.w;
  if (flat >= 0 && flat < (long)BS) map[(int)flat] = p;
}

// One thread = one output float4, swept linearly over the whole 446 MB.
// plane 0..511  -> out0 (b = plane>>6, c = plane&63)
// plane 512..519-> out1 (b = plane-512)
__global__ __launch_bounds__(256) void gather_fill_kernel(
    const int* __restrict__ map,     // [B*S] pillar index or -1
    const float* __restrict__ pf,    // [P, 64]
    const float* __restrict__ vnp,   // [P]
    float* __restrict__ out,
    int total4) {
  int g = blockIdx.x * blockDim.x + threadIdx.x;
  if (g >= total4) return;
  int plane = g / kS4;
  int j = g - plane * kS4;           // float4 index within plane

  float4 v = make_float4(0.f, 0.f, 0.f, 0.f);
  if (plane < kB * kC) {
    int b = plane >> 6;
    int c = plane & 63;
    int4 m = reinterpret_cast<const int4*>(map)[b * kS4 + j];
    if ((m.x >= 0) | (m.y >= 0) | (m.z >= 0) | (m.w >= 0)) {
      if (m.x >= 0) v.x = pf[m.x * kC + c];
      if (m.y >= 0) v.y = pf[m.y * kC + c];
      if (m.z >= 0) v.z = pf[m.z * kC + c];
      if (m.w >= 0) v.w = pf[m.w * kC + c];
    }
  } else {
    int b = plane - kB * kC;
    int4 m = reinterpret_cast<const int4*>(map)[b * kS4 + j];
    if (m.x >= 0) v.x = vnp[m.x];
    if (m.y >= 0) v.y = vnp[m.y];
    if (m.z >= 0) v.z = vnp[m.z];
    if (m.w >= 0) v.w = vnp[m.w];
  }
  reinterpret_cast<float4*>(out)[g] = v;
}

// ---- fallback if ws_size is too small for the map: memset + direct scatter
__global__ void direct_scatter_kernel(const int* __restrict__ coords,
                                      const float* __restrict__ pf,
                                      const float* __restrict__ vnp,
                                      float* __restrict__ out,
                                      int P, int B) {
  int p = blockIdx.x;          // one wave per pillar
  int c = threadIdx.x;         // 64 channels
  if (p >= P) return;
  int4 cc = reinterpret_cast<const int4*>(coords)[p];
  int b = cc.x;
  int s = cc.y + cc.z * kNX + cc.w;
  out[(b * kC + c) * kS + s] = pf[p * kC + c];
  if (c == 0) out[B * kC * kS + b * kS + s] = vnp[p];
}

}  // namespace

extern "C" void kernel_launch(void* const* d_in, const int* in_sizes, int n_in,
                              void* d_out, int out_size, void* d_ws, size_t ws_size,
                              hipStream_t stream) {
  const float* pf     = (const float*)d_in[0];  // [P,64] f32
  const int*   coords = (const int*)d_in[1];    // [P,4] int32 (b,z,y,x)
  const float* vnp    = (const float*)d_in[2];  // [P] f32
  const int B = kB;                              // fixed by problem config
  const int P = in_sizes[0] / kC;
  const int BS = B * kS;                         // 1,714,176
  float* out = (float*)d_out;

  const size_t map_bytes = (size_t)BS * sizeof(int);
  if (ws_size >= map_bytes) {
    int* map = (int*)d_ws;
    hipMemsetAsync(map, 0xFF, map_bytes, stream);  // all -1
    scatter_idx_kernel<<<(P + 255) / 256, 256, 0, stream>>>(coords, map, P, BS);
    const int total4 = (B * kC * kS + B * kS) / 4;  // 27,855,360 float4s
    gather_fill_kernel<<<(total4 + 255) / 256, 256, 0, stream>>>(
        map, pf, vnp, out, total4);
  } else {
    hipMemsetAsync(out, 0, (size_t)out_size * sizeof(float), stream);
    direct_scatter_kernel<<<P, 64, 0, stream>>>(coords, pf, vnp, out, P, B);
  }
}